// Round 2
// baseline (134.240 us; speedup 1.0000x reference)
//
#include <hip/hip_runtime.h>

namespace {

constexpr int kB  = 16384;  // rods
constexpr int kNV = 129;    // vertices per rod
constexpr int kNE = 128;    // edges per rod

struct D3 { double x, y, z; };

__device__ __forceinline__ D3 cross3(const D3 a, const D3 b) {
    return { a.y*b.z - a.z*b.y,
             a.z*b.x - a.x*b.z,
             a.x*b.y - a.y*b.x };
}
__device__ __forceinline__ double dot3(const D3 a, const D3 b) {
    return a.x*b.x + a.y*b.y + a.z*b.z;
}
__device__ __forceinline__ D3 sub3(const D3 a, const D3 b) {
    return { a.x-b.x, a.y-b.y, a.z-b.z };
}
__device__ __forceinline__ D3 scale3(const D3 a, const double s) {
    return { a.x*s, a.y*s, a.z*s };
}
// matches ref _normalize: x / max(|x|, 1e-12)
__device__ __forceinline__ D3 nrm3(const D3 a) {
    const double n = sqrt(dot3(a, a));
    const double m = fmax(n, 1e-12);
    return { a.x/m, a.y/m, a.z/m };
}

__global__ __launch_bounds__(64)
void rod_frames_kernel(const float* __restrict__ verts,   // (B, 129, 3)
                       const float* __restrict__ dinit,   // (B, 3)
                       const float* __restrict__ restL,   // (B, 128)
                       float* __restrict__ out)           // [b_u | b_v | kb], each (B,128,3)
{
    const int b = blockIdx.x * 64 + threadIdx.x;
    if (b >= kB) return;

    const float* V = verts + (size_t)b * (kNV * 3);
    const float* L = restL + (size_t)b * kNE;
    float* bu  = out + (size_t)b * (kNE * 3);
    float* bv  = bu  + (size_t)kB * (kNE * 3);
    float* kbo = bv  + (size_t)kB * (kNE * 3);

    const D3 dv = { (double)dinit[b*3+0], (double)dinit[b*3+1], (double)dinit[b*3+2] };

    D3 pC = { (double)V[0], (double)V[1], (double)V[2] };
    D3 pN = { (double)V[3], (double)V[4], (double)V[5] };
    const D3 e0 = sub3(pN, pC);

    // u0 = normalize(cross(cross(e0, d), e0)); v0 = normalize(cross(e0, u0))
    D3 u = nrm3(cross3(cross3(e0, dv), e0));
    D3 v = nrm3(cross3(e0, u));

    bu[0] = (float)u.x; bu[1] = (float)u.y; bu[2] = (float)u.z;
    bv[0] = (float)v.x; bv[1] = (float)v.y; bv[2] = (float)v.z;
    kbo[0] = 0.0f; kbo[1] = 0.0f; kbo[2] = 0.0f;

    D3 eP = e0;
    double lP = (double)L[0];
    pC = pN;

    for (int i = 1; i < kNE; ++i) {
        pN = D3{ (double)V[(i+1)*3+0], (double)V[(i+1)*3+1], (double)V[(i+1)*3+2] };
        const double li = (double)L[i];
        const D3 e = sub3(pN, pC);

        // denom = lP*li + dot(eP, e): catastrophic cancellation here -> fp64.
        const double denom = lP*li + dot3(eP, e);
        const D3 c = cross3(eP, e);
        const D3 kb = { 2.0*c.x/denom, 2.0*c.y/denom, 2.0*c.z/denom };
        kbo[i*3+0] = (float)kb.x; kbo[i*3+1] = (float)kb.y; kbo[i*3+2] = (float)kb.z;

        const double mag = dot3(kb, kb);
        const double inv = 1.0 / (4.0 + mag);
        const double w   = sqrt(4.0 * inv);

        if (1.0 - w > 1e-6) {   // !cond -> apply rotation, recompute v
            const double sp = sqrt(mag * inv);                  // sinPhi
            // axis = sinPhi * normalize(kb)
            const double nkb = sqrt(mag);
            const double m   = fmax(nkb, 1e-12);
            const D3 ax = { kb.x/m*sp, kb.y/m*sp, kb.z/m*sp };
            // u_rot = u + 2*(w*(ax x u) + ax x (ax x u))
            const D3 t  = cross3(ax, u);
            const D3 t2 = cross3(ax, t);
            u.x += 2.0 * (w * t.x + t2.x);
            u.y += 2.0 * (w * t.y + t2.y);
            u.z += 2.0 * (w * t.z + t2.z);
            v = nrm3(cross3(e, u));
        }
        // cond -> keep previous u, v

        bu[i*3+0] = (float)u.x; bu[i*3+1] = (float)u.y; bu[i*3+2] = (float)u.z;
        bv[i*3+0] = (float)v.x; bv[i*3+1] = (float)v.y; bv[i*3+2] = (float)v.z;

        eP = e; lP = li; pC = pN;
    }
}

} // namespace

extern "C" void kernel_launch(void* const* d_in, const int* in_sizes, int n_in,
                              void* d_out, int out_size, void* d_ws, size_t ws_size,
                              hipStream_t stream)
{
    const float* verts = (const float*)d_in[0];
    const float* dinit = (const float*)d_in[1];
    const float* restL = (const float*)d_in[2];
    float* out = (float*)d_out;

    dim3 grid(kB / 64);
    dim3 block(64);
    hipLaunchKernelGGL(rod_frames_kernel, grid, block, 0, stream,
                       verts, dinit, restL, out);
}

// Round 3
// 41.509 us; speedup vs baseline: 3.2340x; 3.2340x over previous
//
#include <hip/hip_runtime.h>

namespace {

constexpr int kB  = 16384;  // rods
constexpr int kNV = 129;    // vertices per rod
constexpr int kNE = 128;    // edges per rod
constexpr int kRPB = 4;     // rods (= waves) per block

struct D3 { double x, y, z; };
struct Q4 { double w, x, y, z; };

__device__ __forceinline__ D3 sub3(D3 a, D3 b) { return { a.x-b.x, a.y-b.y, a.z-b.z }; }
__device__ __forceinline__ D3 cross3(D3 a, D3 b) {
    return { a.y*b.z - a.z*b.y,
             a.z*b.x - a.x*b.z,
             a.x*b.y - a.y*b.x };
}
__device__ __forceinline__ double dot3(D3 a, D3 b) { return a.x*b.x + a.y*b.y + a.z*b.z; }
// matches ref _normalize: x / max(|x|, 1e-12)
__device__ __forceinline__ D3 nrm3(D3 a) {
    const double m = fmax(sqrt(dot3(a, a)), 1e-12);
    return { a.x/m, a.y/m, a.z/m };
}
// a (x) b : apply b first, then a
__device__ __forceinline__ Q4 qmul(Q4 a, Q4 b) {
    return { a.w*b.w - a.x*b.x - a.y*b.y - a.z*b.z,
             a.w*b.x + a.x*b.w + a.y*b.z - a.z*b.y,
             a.w*b.y - a.x*b.z + a.y*b.w + a.z*b.x,
             a.w*b.z + a.x*b.y - a.y*b.x + a.z*b.w };
}
// rotate x by unit quaternion q: x + 2w(v x x) + 2 v x (v x x)
__device__ __forceinline__ D3 qrot(Q4 q, D3 x) {
    const D3 v  = { q.x, q.y, q.z };
    const D3 t  = cross3(v, x);
    const D3 t2 = cross3(v, t);
    return { x.x + 2.0*(q.w*t.x + t2.x),
             x.y + 2.0*(q.w*t.y + t2.y),
             x.z + 2.0*(q.w*t.z + t2.z) };
}
__device__ __forceinline__ Q4 shflup_q(Q4 a, int d) {
    Q4 r;
    r.w = __shfl_up(a.w, d, 64);
    r.x = __shfl_up(a.x, d, 64);
    r.y = __shfl_up(a.y, d, 64);
    r.z = __shfl_up(a.z, d, 64);
    return r;
}

__global__ __launch_bounds__(256)
void rod_frames_scan_kernel(const float* __restrict__ verts,   // (B, 129, 3)
                            const float* __restrict__ dinit,   // (B, 3)
                            const float* __restrict__ restL,   // (B, 128)
                            float* __restrict__ out)           // [b_u | b_v | kb]
{
    const int wave = threadIdx.x >> 6;
    const int lane = threadIdx.x & 63;
    const int b = blockIdx.x * kRPB + wave;

    __shared__ float sv[kRPB][kNV*3 + 1];   // rod vertices, fp32 (exact to promote)

    // ---- cooperative stage: this wave loads its own rod (coalesced) ----
    const float* V = verts + (size_t)b * (kNV*3);
    for (int k = lane; k < kNV*3; k += 64) sv[wave][k] = V[k];
    __syncthreads();

    auto ldv = [&](int vi) -> D3 {
        return { (double)sv[wave][vi*3+0],
                 (double)sv[wave][vi*3+1],
                 (double)sv[wave][vi*3+2] };
    };

    const int i0 = 2*lane, i1 = 2*lane + 1;

    // ---- edges for my two slots (fp64 subtraction of exact fp32 values) ----
    const D3 vA = ldv(i0);
    const D3 vB = ldv(i0+1);
    const D3 vC = ldv(i0+2);
    const D3 eA = sub3(vB, vA);   // e_{i0}
    const D3 eB = sub3(vC, vB);   // e_{i1}

    // ---- u0 (identical in every lane) ----
    const D3 dv  = { (double)dinit[b*3+0], (double)dinit[b*3+1], (double)dinit[b*3+2] };
    const D3 p0  = ldv(0);
    const D3 p1  = ldv(1);
    const D3 e0  = sub3(p1, p0);
    const D3 u0  = nrm3(cross3(cross3(e0, dv), e0));

    // ---- rest lengths ----
    const float* L = restL + (size_t)b * kNE;
    const double lA = (double)L[i0];
    const double lB = (double)L[i1];
    const double lP = __shfl_up(lB, 1, 64);   // L[i0-1] (lane 0: unused)

    // ---- per-slot kb, quaternion, activity ----
    D3  kb0 = {0.0, 0.0, 0.0};
    Q4  q0  = {1.0, 0.0, 0.0, 0.0};
    bool act0 = (lane == 0);          // index 0 is the u0/v0 anchor
    if (lane > 0) {
        const D3 vP = ldv(i0-1);
        const D3 eP = sub3(vA, vP);   // e_{i0-1}
        const double denom = lP*lA + dot3(eP, eA);
        const D3 c = cross3(eP, eA);
        kb0 = { 2.0*c.x/denom, 2.0*c.y/denom, 2.0*c.z/denom };
        const double mag = dot3(kb0, kb0);
        const double inv = 1.0 / (4.0 + mag);
        const double w   = sqrt(4.0 * inv);
        if (1.0 - w > 1e-6) {
            act0 = true;
            const double sp = sqrt(mag * inv);
            const double m  = fmax(sqrt(mag), 1e-12);
            q0 = { w, kb0.x/m*sp, kb0.y/m*sp, kb0.z/m*sp };
        }
    }

    D3  kb1;
    Q4  q1  = {1.0, 0.0, 0.0, 0.0};
    bool act1 = false;
    {
        const double denom = lA*lB + dot3(eA, eB);
        const D3 c = cross3(eA, eB);
        kb1 = { 2.0*c.x/denom, 2.0*c.y/denom, 2.0*c.z/denom };
        const double mag = dot3(kb1, kb1);
        const double inv = 1.0 / (4.0 + mag);
        const double w   = sqrt(4.0 * inv);
        if (1.0 - w > 1e-6) {
            act1 = true;
            const double sp = sqrt(mag * inv);
            const double m  = fmax(sqrt(mag), 1e-12);
            q1 = { w, kb1.x/m*sp, kb1.y/m*sp, kb1.z/m*sp };
        }
    }

    // ---- Kogge-Stone inclusive scan of quaternion products across the wave ----
    const Q4 loc = qmul(q1, q0);
    Q4 s = loc;
    #pragma unroll
    for (int d = 1; d < 64; d <<= 1) {
        const Q4 t = shflup_q(s, d);
        if (lane >= d) s = qmul(s, t);
    }
    Q4 ex = shflup_q(s, 1);
    if (lane == 0) ex = {1.0, 0.0, 0.0, 0.0};
    const Q4 Qa = qmul(q0, ex);   // composed rotation up to index i0
    const Q4 Qb = s;              // composed rotation up to index i1

    // ---- int max-scan for "last active index" (v-carry resolution) ----
    const int a0 = act0 ? i0 : -1;
    const int a1 = act1 ? i1 : -1;
    const int la = max(a0, a1);
    int m = la;
    #pragma unroll
    for (int d = 1; d < 64; d <<= 1) {
        const int t = __shfl_up(m, d, 64);
        if (lane >= d) m = max(m, t);
    }
    int exm = __shfl_up(m, 1, 64);
    if (lane == 0) exm = -1;
    const int j0 = max(exm, a0);   // >= 0 always (index 0 active)
    const int j1 = max(exm, la);

    // ---- u_i = R(Q_i) u0 ; v_i = normalize(cross(e_{j_i}, u_i)) ----
    const D3 uA = qrot(Qa, u0);
    const D3 uB = qrot(Qb, u0);

    auto edge_at = [&](int j) -> D3 {
        const D3 p = ldv(j);
        const D3 q = ldv(j+1);
        return sub3(q, p);
    };
    const D3 vvA = nrm3(cross3(edge_at(j0), uA));
    const D3 vvB = nrm3(cross3(edge_at(j1), uB));

    // ---- coalesced stores: 6 consecutive floats per lane per array ----
    float* bu  = out + (size_t)b * (kNE*3);
    float* bv  = bu  + (size_t)kB * (kNE*3);
    float* kbo = bv  + (size_t)kB * (kNE*3);
    const int o = 6*lane;

    *(float2*)(bu  + o    ) = make_float2((float)uA.x, (float)uA.y);
    *(float2*)(bu  + o + 2) = make_float2((float)uA.z, (float)uB.x);
    *(float2*)(bu  + o + 4) = make_float2((float)uB.y, (float)uB.z);

    *(float2*)(bv  + o    ) = make_float2((float)vvA.x, (float)vvA.y);
    *(float2*)(bv  + o + 2) = make_float2((float)vvA.z, (float)vvB.x);
    *(float2*)(bv  + o + 4) = make_float2((float)vvB.y, (float)vvB.z);

    *(float2*)(kbo + o    ) = make_float2((float)kb0.x, (float)kb0.y);
    *(float2*)(kbo + o + 2) = make_float2((float)kb0.z, (float)kb1.x);
    *(float2*)(kbo + o + 4) = make_float2((float)kb1.y, (float)kb1.z);
}

} // namespace

extern "C" void kernel_launch(void* const* d_in, const int* in_sizes, int n_in,
                              void* d_out, int out_size, void* d_ws, size_t ws_size,
                              hipStream_t stream)
{
    const float* verts = (const float*)d_in[0];
    const float* dinit = (const float*)d_in[1];
    const float* restL = (const float*)d_in[2];
    float* out = (float*)d_out;

    dim3 grid(kB / kRPB);
    dim3 block(64 * kRPB);
    hipLaunchKernelGGL(rod_frames_scan_kernel, grid, block, 0, stream,
                       verts, dinit, restL, out);
}

// Round 4
// 32.457 us; speedup vs baseline: 4.1359x; 1.2789x over previous
//
#include <hip/hip_runtime.h>

namespace {

constexpr int kB  = 16384;  // rods
constexpr int kNV = 129;    // vertices per rod
constexpr int kNE = 128;    // edges per rod
constexpr int kRPB = 4;     // rods (= waves) per block

struct F3 { float x, y, z; };
struct D3 { double x, y, z; };
struct Q4 { float w, x, y, z; };   // fp32 quaternion

__device__ __forceinline__ F3 subf(F3 a, F3 b) { return { a.x-b.x, a.y-b.y, a.z-b.z }; }
__device__ __forceinline__ F3 crossf(F3 a, F3 b) {
    return { a.y*b.z - a.z*b.y,
             a.z*b.x - a.x*b.z,
             a.x*b.y - a.y*b.x };
}
__device__ __forceinline__ float dotf(F3 a, F3 b) { return a.x*b.x + a.y*b.y + a.z*b.z; }
// matches ref _normalize: x / max(|x|, 1e-12)
__device__ __forceinline__ F3 nrmf(F3 a) {
    const float s = 1.0f / fmaxf(sqrtf(dotf(a, a)), 1e-12f);
    return { a.x*s, a.y*s, a.z*s };
}
// a (x) b : apply b first, then a
__device__ __forceinline__ Q4 qmul(Q4 a, Q4 b) {
    return { a.w*b.w - a.x*b.x - a.y*b.y - a.z*b.z,
             a.w*b.x + a.x*b.w + a.y*b.z - a.z*b.y,
             a.w*b.y - a.x*b.z + a.y*b.w + a.z*b.x,
             a.w*b.z + a.x*b.y - a.y*b.x + a.z*b.w };
}
// rotate x by unit quaternion q: x + 2w(v x x) + 2 v x (v x x)
__device__ __forceinline__ F3 qrot(Q4 q, F3 x) {
    const F3 v  = { q.x, q.y, q.z };
    const F3 t  = crossf(v, x);
    const F3 t2 = crossf(v, t);
    return { x.x + 2.0f*(q.w*t.x + t2.x),
             x.y + 2.0f*(q.w*t.y + t2.y),
             x.z + 2.0f*(q.w*t.z + t2.z) };
}
__device__ __forceinline__ Q4 shflup_q(Q4 a, int d) {
    Q4 r;
    r.w = __shfl_up(a.w, d, 64);
    r.x = __shfl_up(a.x, d, 64);
    r.y = __shfl_up(a.y, d, 64);
    r.z = __shfl_up(a.z, d, 64);
    return r;
}

__global__ __launch_bounds__(256)
void rod_frames_scan_kernel(const float* __restrict__ verts,   // (B, 129, 3)
                            const float* __restrict__ dinit,   // (B, 3)
                            const float* __restrict__ restL,   // (B, 128)
                            float* __restrict__ out)           // [b_u | b_v | kb]
{
    const int wave = threadIdx.x >> 6;
    const int lane = threadIdx.x & 63;
    const int b = blockIdx.x * kRPB + wave;

    __shared__ float sv[kRPB][kNV*3 + 1];   // rod vertices, fp32

    // ---- cooperative stage: this wave loads its own rod (coalesced) ----
    const float* V = verts + (size_t)b * (kNV*3);
    for (int k = lane; k < kNV*3; k += 64) sv[wave][k] = V[k];
    __syncthreads();

    auto ldf = [&](int vi) -> F3 {
        return { sv[wave][vi*3+0], sv[wave][vi*3+1], sv[wave][vi*3+2] };
    };
    auto ldd = [&](int vi) -> D3 {
        return { (double)sv[wave][vi*3+0],
                 (double)sv[wave][vi*3+1],
                 (double)sv[wave][vi*3+2] };
    };

    const int i0 = 2*lane, i1 = 2*lane + 1;

    // ---- fp64 edges (exact: fp32 values promote exactly, diffs fit 53 bits)
    //      needed ONLY for the cancellation-critical denominators ----
    const D3 dA = ldd(i0);
    const D3 dB = ldd(i0+1);
    const D3 dC = ldd(i0+2);
    const D3 eAd = { dB.x-dA.x, dB.y-dA.y, dB.z-dA.z };
    const D3 eBd = { dC.x-dB.x, dC.y-dB.y, dC.z-dB.z };
    const F3 eAf = { (float)eAd.x, (float)eAd.y, (float)eAd.z };
    const F3 eBf = { (float)eBd.x, (float)eBd.y, (float)eBd.z };

    // ---- u0 (identical in every lane), fp32 ----
    const F3 dvf = { dinit[b*3+0], dinit[b*3+1], dinit[b*3+2] };
    const F3 p0  = ldf(0);
    const F3 p1  = ldf(1);
    const F3 e0f = subf(p1, p0);
    const F3 u0  = nrmf(crossf(crossf(e0f, dvf), e0f));

    // ---- rest lengths ----
    const float2 Lp = *(const float2*)(restL + (size_t)b*kNE + i0);
    const double lA = (double)Lp.x;
    const double lB = (double)Lp.y;
    const double lPd = __shfl_up(lB, 1, 64);   // L[i0-1] (lane 0: unused)

    // ---- per-slot kb (fp64 denom, fp32 numerator), quaternion, activity ----
    F3  kb0 = {0.f, 0.f, 0.f};
    Q4  q0  = {1.f, 0.f, 0.f, 0.f};
    bool act0 = (lane == 0);          // index 0 is the u0/v0 anchor
    if (lane > 0) {
        const D3 dP = ldd(i0-1);
        const D3 ePd = { dA.x-dP.x, dA.y-dP.y, dA.z-dP.z };
        const double denom = lPd*lA + (ePd.x*eAd.x + ePd.y*eAd.y + ePd.z*eAd.z);
        const F3 ePf = { (float)ePd.x, (float)ePd.y, (float)ePd.z };
        const F3 c = crossf(ePf, eAf);
        const float rd = 2.0f / (float)denom;
        kb0 = { c.x*rd, c.y*rd, c.z*rd };
        const float mag = dotf(kb0, kb0);
        const float inv = 1.0f / (4.0f + mag);
        const float w   = sqrtf(4.0f * inv);
        if (1.0f - w > 1e-6f) {
            act0 = true;
            const float sp = sqrtf(mag * inv);                    // sinPhi
            const float as = sp / fmaxf(sqrtf(mag), 1e-12f);      // sinPhi/|kb|
            q0 = { w, kb0.x*as, kb0.y*as, kb0.z*as };
        }
    }

    F3  kb1;
    Q4  q1  = {1.f, 0.f, 0.f, 0.f};
    bool act1 = false;
    {
        const double denom = lA*lB + (eAd.x*eBd.x + eAd.y*eBd.y + eAd.z*eBd.z);
        const F3 c = crossf(eAf, eBf);
        const float rd = 2.0f / (float)denom;
        kb1 = { c.x*rd, c.y*rd, c.z*rd };
        const float mag = dotf(kb1, kb1);
        const float inv = 1.0f / (4.0f + mag);
        const float w   = sqrtf(4.0f * inv);
        if (1.0f - w > 1e-6f) {
            act1 = true;
            const float sp = sqrtf(mag * inv);
            const float as = sp / fmaxf(sqrtf(mag), 1e-12f);
            q1 = { w, kb1.x*as, kb1.y*as, kb1.z*as };
        }
    }

    // ---- Kogge-Stone inclusive scan of quaternion products (fp32) ----
    Q4 s = qmul(q1, q0);
    #pragma unroll
    for (int d = 1; d < 64; d <<= 1) {
        const Q4 t = shflup_q(s, d);
        if (lane >= d) s = qmul(s, t);
    }
    Q4 ex = shflup_q(s, 1);
    if (lane == 0) ex = {1.f, 0.f, 0.f, 0.f};
    const Q4 Qa = qmul(q0, ex);   // composed rotation up to index i0
    const Q4 Qb = s;              // composed rotation up to index i1

    // ---- int max-scan for "last active index" (v-carry resolution) ----
    const int a0 = act0 ? i0 : -1;
    const int a1 = act1 ? i1 : -1;
    const int la = max(a0, a1);
    int m = la;
    #pragma unroll
    for (int d = 1; d < 64; d <<= 1) {
        const int t = __shfl_up(m, d, 64);
        if (lane >= d) m = max(m, t);
    }
    int exm = __shfl_up(m, 1, 64);
    if (lane == 0) exm = -1;
    const int j0 = max(exm, a0);   // >= 0 always (index 0 active)
    const int j1 = max(exm, la);

    // ---- u_i = R(Q_i) u0 ; v_i = normalize(cross(e_{j_i}, u_i)) ----
    const F3 uA = qrot(Qa, u0);
    const F3 uB = qrot(Qb, u0);

    auto edge_at = [&](int j) -> F3 {
        return subf(ldf(j+1), ldf(j));
    };
    const F3 vvA = nrmf(crossf(edge_at(j0), uA));
    const F3 vvB = nrmf(crossf(edge_at(j1), uB));

    // ---- coalesced stores: 6 consecutive floats per lane per array ----
    float* bu  = out + (size_t)b * (kNE*3);
    float* bv  = bu  + (size_t)kB * (kNE*3);
    float* kbo = bv  + (size_t)kB * (kNE*3);
    const int o = 6*lane;

    *(float2*)(bu  + o    ) = make_float2(uA.x, uA.y);
    *(float2*)(bu  + o + 2) = make_float2(uA.z, uB.x);
    *(float2*)(bu  + o + 4) = make_float2(uB.y, uB.z);

    *(float2*)(bv  + o    ) = make_float2(vvA.x, vvA.y);
    *(float2*)(bv  + o + 2) = make_float2(vvA.z, vvB.x);
    *(float2*)(bv  + o + 4) = make_float2(vvB.y, vvB.z);

    *(float2*)(kbo + o    ) = make_float2(kb0.x, kb0.y);
    *(float2*)(kbo + o + 2) = make_float2(kb0.z, kb1.x);
    *(float2*)(kbo + o + 4) = make_float2(kb1.y, kb1.z);
}

} // namespace

extern "C" void kernel_launch(void* const* d_in, const int* in_sizes, int n_in,
                              void* d_out, int out_size, void* d_ws, size_t ws_size,
                              hipStream_t stream)
{
    const float* verts = (const float*)d_in[0];
    const float* dinit = (const float*)d_in[1];
    const float* restL = (const float*)d_in[2];
    float* out = (float*)d_out;

    dim3 grid(kB / kRPB);
    dim3 block(64 * kRPB);
    hipLaunchKernelGGL(rod_frames_scan_kernel, grid, block, 0, stream,
                       verts, dinit, restL, out);
}

// Round 5
// 29.210 us; speedup vs baseline: 4.5956x; 1.1111x over previous
//
#include <hip/hip_runtime.h>

namespace {

constexpr int kB  = 16384;  // rods
constexpr int kNV = 129;    // vertices per rod
constexpr int kNE = 128;    // edges per rod
constexpr int kRPB = 4;     // rods (= waves) per block

struct F3 { float x, y, z; };
struct Q4 { float w, x, y, z; };   // fp32 quaternion

__device__ __forceinline__ F3 crossf(F3 a, F3 b) {
    return { a.y*b.z - a.z*b.y,
             a.z*b.x - a.x*b.z,
             a.x*b.y - a.y*b.x };
}
__device__ __forceinline__ float dotf(F3 a, F3 b) { return a.x*b.x + a.y*b.y + a.z*b.z; }
__device__ __forceinline__ F3 subf(F3 a, F3 b) { return { a.x-b.x, a.y-b.y, a.z-b.z }; }
// matches ref _normalize: x / max(|x|, 1e-12)
__device__ __forceinline__ F3 nrmf(F3 a) {
    const float s = 1.0f / fmaxf(sqrtf(dotf(a, a)), 1e-12f);
    return { a.x*s, a.y*s, a.z*s };
}
// a (x) b : apply b first, then a
__device__ __forceinline__ Q4 qmul(Q4 a, Q4 b) {
    return { a.w*b.w - a.x*b.x - a.y*b.y - a.z*b.z,
             a.w*b.x + a.x*b.w + a.y*b.z - a.z*b.y,
             a.w*b.y - a.x*b.z + a.y*b.w + a.z*b.x,
             a.w*b.z + a.x*b.y - a.y*b.x + a.z*b.w };
}
// rotate x by unit quaternion q: x + 2w(v x x) + 2 v x (v x x)
__device__ __forceinline__ F3 qrot(Q4 q, F3 x) {
    const F3 v  = { q.x, q.y, q.z };
    const F3 t  = crossf(v, x);
    const F3 t2 = crossf(v, t);
    return { x.x + 2.0f*(q.w*t.x + t2.x),
             x.y + 2.0f*(q.w*t.y + t2.y),
             x.z + 2.0f*(q.w*t.z + t2.z) };
}
__device__ __forceinline__ Q4 shflup_q(Q4 a, int d) {
    Q4 r;
    r.w = __shfl_up(a.w, d, 64);
    r.x = __shfl_up(a.x, d, 64);
    r.y = __shfl_up(a.y, d, 64);
    r.z = __shfl_up(a.z, d, 64);
    return r;
}
// highest set bit index, m != 0
__device__ __forceinline__ int hbit(unsigned long long m) {
    return 63 - __builtin_clzll(m);
}

__global__ __launch_bounds__(256)
void rod_frames_scan_kernel(const float* __restrict__ verts,   // (B, 129, 3)
                            const float* __restrict__ dinit,   // (B, 3)
                            const float* __restrict__ restL,   // (B, 128)
                            float* __restrict__ out)           // [b_u | b_v | kb]
{
    const int wave = threadIdx.x >> 6;
    const int lane = threadIdx.x & 63;
    const int b = blockIdx.x * kRPB + wave;

    const int i0 = 2*lane, i1 = 2*lane + 1;

    // ---- direct per-lane vertex loads (no LDS, no barrier) ----
    // lane needs vertices i0-1 (clamped), i0, i0+1, i0+2; lane 63's vC = vertex 128 (exists).
    const float* V = verts + (size_t)b * (kNV*3);
    const int pidx = (lane > 0 ? i0-1 : 0) * 3;
    const F3 vP = { V[pidx  ], V[pidx+1], V[pidx+2] };
    const F3 vA = { V[i0*3  ], V[i0*3+1], V[i0*3+2] };
    const F3 vB = { V[i0*3+3], V[i0*3+4], V[i0*3+5] };
    const F3 vC = { V[i0*3+6], V[i0*3+7], V[i0*3+8] };

    // ---- fp64 edges (exact: fp32 promotes exactly, diffs fit 53 bits) ----
    const double eAdx = (double)vB.x - (double)vA.x;
    const double eAdy = (double)vB.y - (double)vA.y;
    const double eAdz = (double)vB.z - (double)vA.z;
    const double eBdx = (double)vC.x - (double)vB.x;
    const double eBdy = (double)vC.y - (double)vB.y;
    const double eBdz = (double)vC.z - (double)vB.z;
    const double ePdx = (double)vA.x - (double)vP.x;
    const double ePdy = (double)vA.y - (double)vP.y;
    const double ePdz = (double)vA.z - (double)vP.z;
    const F3 eAf = { (float)eAdx, (float)eAdy, (float)eAdz };
    const F3 eBf = { (float)eBdx, (float)eBdy, (float)eBdz };
    const F3 ePf = { (float)ePdx, (float)ePdy, (float)ePdz };

    // ---- u0 (identical in every lane), fp32 ----
    const int bw = __builtin_amdgcn_readfirstlane(b);
    const F3 dvf = { dinit[bw*3+0], dinit[bw*3+1], dinit[bw*3+2] };
    const F3 p0  = { V[0], V[1], V[2] };
    const F3 p1  = { V[3], V[4], V[5] };
    const F3 e0f = subf(p1, p0);
    const F3 u0  = nrmf(crossf(crossf(e0f, dvf), e0f));

    // ---- rest lengths ----
    const float* L = restL + (size_t)b * kNE;
    const double lP = (double)L[lane > 0 ? i0-1 : 0];
    const double lA = (double)L[i0];
    const double lB = (double)L[i1];

    // ---- per-slot kb (fp64 denom, fp32 numerator), quaternion, activity ----
    F3  kb0 = {0.f, 0.f, 0.f};
    Q4  q0  = {1.f, 0.f, 0.f, 0.f};
    bool act0 = (lane == 0);          // index 0 is the u0/v0 anchor
    if (lane > 0) {
        const double denom = lP*lA + (ePdx*eAdx + ePdy*eAdy + ePdz*eAdz);
        const F3 c = crossf(ePf, eAf);
        const float rd = 2.0f / (float)denom;
        kb0 = { c.x*rd, c.y*rd, c.z*rd };
        const float mag = dotf(kb0, kb0);
        const float inv = 1.0f / (4.0f + mag);
        const float w   = sqrtf(4.0f * inv);
        if (1.0f - w > 1e-6f) {
            act0 = true;
            const float sp = sqrtf(mag * inv);                    // sinPhi
            const float as = sp / fmaxf(sqrtf(mag), 1e-12f);      // sinPhi/|kb|
            q0 = { w, kb0.x*as, kb0.y*as, kb0.z*as };
        }
    }

    F3  kb1;
    Q4  q1  = {1.f, 0.f, 0.f, 0.f};
    bool act1 = false;
    {
        const double denom = lA*lB + (eAdx*eBdx + eAdy*eBdy + eAdz*eBdz);
        const F3 c = crossf(eAf, eBf);
        const float rd = 2.0f / (float)denom;
        kb1 = { c.x*rd, c.y*rd, c.z*rd };
        const float mag = dotf(kb1, kb1);
        const float inv = 1.0f / (4.0f + mag);
        const float w   = sqrtf(4.0f * inv);
        if (1.0f - w > 1e-6f) {
            act1 = true;
            const float sp = sqrtf(mag * inv);
            const float as = sp / fmaxf(sqrtf(mag), 1e-12f);
            q1 = { w, kb1.x*as, kb1.y*as, kb1.z*as };
        }
    }

    // ---- Kogge-Stone inclusive scan of quaternion products (fp32) ----
    Q4 s = qmul(q1, q0);
    #pragma unroll
    for (int d = 1; d < 64; d <<= 1) {
        const Q4 t = shflup_q(s, d);
        if (lane >= d) s = qmul(s, t);
    }
    Q4 ex = shflup_q(s, 1);
    if (lane == 0) ex = {1.f, 0.f, 0.f, 0.f};
    const Q4 Qa = qmul(q0, ex);   // composed rotation up to index i0
    const Q4 Qb = s;              // composed rotation up to index i1

    // ---- last-active-index via ballot + clz (replaces shfl max-scan) ----
    const unsigned long long mask0 = __ballot(act0);   // bit l = act at slot 2l
    const unsigned long long mask1 = __ballot(act1);   // bit l = act at slot 2l+1
    // slot i0: act0 lanes <= l, act1 lanes < l
    const unsigned long long m0a = mask0 & (~0ull >> (63 - lane));          // bits 0..l (nonempty: bit0 set)
    const unsigned long long m1a = lane ? (mask1 & (~0ull >> (64 - lane))) : 0ull; // bits 0..l-1
    const int j0 = max(2*hbit(m0a), m1a ? 2*hbit(m1a)+1 : -1);
    // slot i1: act0 lanes <= l, act1 lanes <= l
    const unsigned long long m1b = mask1 & (~0ull >> (63 - lane));          // bits 0..l
    const int j1 = max(2*hbit(m0a), m1b ? 2*hbit(m1b)+1 : -1);

    // ---- u_i = R(Q_i) u0 ----
    const F3 uA = qrot(Qa, u0);
    const F3 uB = qrot(Qb, u0);

    // ---- edges at j0/j1: almost always own eA/eB; rare wave-uniform gather ----
    F3 ej0 = eAf, ej1 = eBf;
    if (__any((j0 != i0) || (j1 != i1))) {
        const int s0 = j0 >> 1, s1 = j1 >> 1;
        const F3 a0 = { __shfl(eAf.x, s0, 64), __shfl(eAf.y, s0, 64), __shfl(eAf.z, s0, 64) };
        const F3 b0 = { __shfl(eBf.x, s0, 64), __shfl(eBf.y, s0, 64), __shfl(eBf.z, s0, 64) };
        const F3 a1 = { __shfl(eAf.x, s1, 64), __shfl(eAf.y, s1, 64), __shfl(eAf.z, s1, 64) };
        const F3 b1 = { __shfl(eBf.x, s1, 64), __shfl(eBf.y, s1, 64), __shfl(eBf.z, s1, 64) };
        ej0 = (j0 & 1) ? b0 : a0;
        ej1 = (j1 & 1) ? b1 : a1;
    }

    const F3 vvA = nrmf(crossf(ej0, uA));
    const F3 vvB = nrmf(crossf(ej1, uB));

    // ---- coalesced stores: 6 consecutive floats per lane per array ----
    float* bu  = out + (size_t)b * (kNE*3);
    float* bv  = bu  + (size_t)kB * (kNE*3);
    float* kbo = bv  + (size_t)kB * (kNE*3);
    const int o = 6*lane;

    *(float2*)(bu  + o    ) = make_float2(uA.x, uA.y);
    *(float2*)(bu  + o + 2) = make_float2(uA.z, uB.x);
    *(float2*)(bu  + o + 4) = make_float2(uB.y, uB.z);

    *(float2*)(bv  + o    ) = make_float2(vvA.x, vvA.y);
    *(float2*)(bv  + o + 2) = make_float2(vvA.z, vvB.x);
    *(float2*)(bv  + o + 4) = make_float2(vvB.y, vvB.z);

    *(float2*)(kbo + o    ) = make_float2(kb0.x, kb0.y);
    *(float2*)(kbo + o + 2) = make_float2(kb0.z, kb1.x);
    *(float2*)(kbo + o + 4) = make_float2(kb1.y, kb1.z);
}

} // namespace

extern "C" void kernel_launch(void* const* d_in, const int* in_sizes, int n_in,
                              void* d_out, int out_size, void* d_ws, size_t ws_size,
                              hipStream_t stream)
{
    const float* verts = (const float*)d_in[0];
    const float* dinit = (const float*)d_in[1];
    const float* restL = (const float*)d_in[2];
    float* out = (float*)d_out;

    dim3 grid(kB / kRPB);
    dim3 block(64 * kRPB);
    hipLaunchKernelGGL(rod_frames_scan_kernel, grid, block, 0, stream,
                       verts, dinit, restL, out);
}

// Round 7
// 27.220 us; speedup vs baseline: 4.9317x; 1.0731x over previous
//
#include <hip/hip_runtime.h>

namespace {

constexpr int kB  = 16384;  // rods
constexpr int kNV = 129;    // vertices per rod
constexpr int kNE = 128;    // edges per rod
constexpr int kRPB = 4;     // rods (= waves) per block

typedef float v2f __attribute__((ext_vector_type(2)));   // NT-store-compatible

struct F3 { float x, y, z; };
struct Q4 { float w, x, y, z; };   // fp32 quaternion

__device__ __forceinline__ F3 crossf(F3 a, F3 b) {
    return { a.y*b.z - a.z*b.y,
             a.z*b.x - a.x*b.z,
             a.x*b.y - a.y*b.x };
}
__device__ __forceinline__ float dotf(F3 a, F3 b) { return a.x*b.x + a.y*b.y + a.z*b.z; }
__device__ __forceinline__ F3 subf(F3 a, F3 b) { return { a.x-b.x, a.y-b.y, a.z-b.z }; }
// matches ref _normalize: x / max(|x|, 1e-12)
__device__ __forceinline__ F3 nrmf(F3 a) {
    const float s = 1.0f / fmaxf(sqrtf(dotf(a, a)), 1e-12f);
    return { a.x*s, a.y*s, a.z*s };
}
// a (x) b : apply b first, then a
__device__ __forceinline__ Q4 qmul(Q4 a, Q4 b) {
    return { a.w*b.w - a.x*b.x - a.y*b.y - a.z*b.z,
             a.w*b.x + a.x*b.w + a.y*b.z - a.z*b.y,
             a.w*b.y - a.x*b.z + a.y*b.w + a.z*b.x,
             a.w*b.z + a.x*b.y - a.y*b.x + a.z*b.w };
}
// rotate x by unit quaternion q: x + 2w(v x x) + 2 v x (v x x)
__device__ __forceinline__ F3 qrot(Q4 q, F3 x) {
    const F3 v  = { q.x, q.y, q.z };
    const F3 t  = crossf(v, x);
    const F3 t2 = crossf(v, t);
    return { x.x + 2.0f*(q.w*t.x + t2.x),
             x.y + 2.0f*(q.w*t.y + t2.y),
             x.z + 2.0f*(q.w*t.z + t2.z) };
}
__device__ __forceinline__ Q4 shflup_q(Q4 a, int d) {
    Q4 r;
    r.w = __shfl_up(a.w, d, 64);
    r.x = __shfl_up(a.x, d, 64);
    r.y = __shfl_up(a.y, d, 64);
    r.z = __shfl_up(a.z, d, 64);
    return r;
}
// highest set bit index, m != 0
__device__ __forceinline__ int hbit(unsigned long long m) {
    return 63 - __builtin_clzll(m);
}
__device__ __forceinline__ void nts2(float* p, float a, float bq) {
    v2f v = { a, bq };
    __builtin_nontemporal_store(v, (v2f*)p);
}

__global__ __launch_bounds__(256)
void rod_frames_scan_kernel(const float* __restrict__ verts,   // (B, 129, 3)
                            const float* __restrict__ dinit,   // (B, 3)
                            const float* __restrict__ restL,   // (B, 128)
                            float* __restrict__ out)           // [b_u | b_v | kb]
{
    const int wave = threadIdx.x >> 6;
    const int lane = threadIdx.x & 63;
    const int b = blockIdx.x * kRPB + wave;

    const int i0 = 2*lane, i1 = 2*lane + 1;

    // ---- per-lane vertex loads: ONLY own 2 vertices (3x float2, 8B aligned) ----
    const float2* V2 = (const float2*)(verts + (size_t)b * (kNV*3));
    const float2 f0 = V2[3*lane + 0];
    const float2 f1 = V2[3*lane + 1];
    const float2 f2 = V2[3*lane + 2];
    const F3 vA = { f0.x, f0.y, f1.x };   // vertex 2l
    const F3 vB = { f1.y, f2.x, f2.y };   // vertex 2l+1

    // ---- wave-uniform reads -> scalar pipe ----
    const int bw = __builtin_amdgcn_readfirstlane(b);
    const float* Vu = verts + (size_t)bw * (kNV*3);
    const F3 vLast = { Vu[kNE*3+0], Vu[kNE*3+1], Vu[kNE*3+2] };   // vertex 128
    const F3 dvf   = { dinit[bw*3+0], dinit[bw*3+1], dinit[bw*3+2] };
    const F3 p0    = { Vu[0], Vu[1], Vu[2] };
    const F3 p1    = { Vu[3], Vu[4], Vu[5] };

    // ---- vC (vertex 2l+2) from neighbor lane; lane 63 takes vertex 128 ----
    F3 vC;
    vC.x = __shfl_down(vA.x, 1, 64);
    vC.y = __shfl_down(vA.y, 1, 64);
    vC.z = __shfl_down(vA.z, 1, 64);
    if (lane == 63) vC = vLast;

    // ---- fp64 edges (exact: fp32 promotes exactly, diffs fit 53 bits) ----
    const double eAdx = (double)vB.x - (double)vA.x;   // e_{2l}
    const double eAdy = (double)vB.y - (double)vA.y;
    const double eAdz = (double)vB.z - (double)vA.z;
    const double eBdx = (double)vC.x - (double)vB.x;   // e_{2l+1}
    const double eBdy = (double)vC.y - (double)vB.y;
    const double eBdz = (double)vC.z - (double)vB.z;
    // e_{2l-1} = previous lane's eB (bit-identical to loading vP and subtracting)
    const double ePdx = __shfl_up(eBdx, 1, 64);
    const double ePdy = __shfl_up(eBdy, 1, 64);
    const double ePdz = __shfl_up(eBdz, 1, 64);

    const F3 eAf = { (float)eAdx, (float)eAdy, (float)eAdz };
    const F3 eBf = { (float)eBdx, (float)eBdy, (float)eBdz };
    const F3 ePf = { (float)ePdx, (float)ePdy, (float)ePdz };

    // ---- u0 (identical in every lane), fp32 ----
    const F3 e0f = subf(p1, p0);
    const F3 u0  = nrmf(crossf(crossf(e0f, dvf), e0f));

    // ---- rest lengths: own pair + neighbor's high half ----
    const float2 Lp = *(const float2*)(restL + (size_t)b*kNE + i0);
    const float lPf = __shfl_up(Lp.y, 1, 64);   // L[i0-1] (lane 0: unused)
    const double lA = (double)Lp.x;
    const double lB = (double)Lp.y;
    const double lP = (double)lPf;

    // ---- per-slot kb (fp64 denom, fp32 numerator), quaternion, activity ----
    F3  kb0 = {0.f, 0.f, 0.f};
    Q4  q0  = {1.f, 0.f, 0.f, 0.f};
    bool act0 = (lane == 0);          // index 0 is the u0/v0 anchor
    if (lane > 0) {
        const double denom = lP*lA + (ePdx*eAdx + ePdy*eAdy + ePdz*eAdz);
        const F3 c = crossf(ePf, eAf);
        const float rd = 2.0f / (float)denom;
        kb0 = { c.x*rd, c.y*rd, c.z*rd };
        const float mag = dotf(kb0, kb0);
        const float inv = 1.0f / (4.0f + mag);
        const float w   = sqrtf(4.0f * inv);
        if (1.0f - w > 1e-6f) {
            act0 = true;
            const float sp = sqrtf(mag * inv);                    // sinPhi
            const float as = sp / fmaxf(sqrtf(mag), 1e-12f);      // sinPhi/|kb|
            q0 = { w, kb0.x*as, kb0.y*as, kb0.z*as };
        }
    }

    F3  kb1;
    Q4  q1  = {1.f, 0.f, 0.f, 0.f};
    bool act1 = false;
    {
        const double denom = lA*lB + (eAdx*eBdx + eAdy*eBdy + eAdz*eBdz);
        const F3 c = crossf(eAf, eBf);
        const float rd = 2.0f / (float)denom;
        kb1 = { c.x*rd, c.y*rd, c.z*rd };
        const float mag = dotf(kb1, kb1);
        const float inv = 1.0f / (4.0f + mag);
        const float w   = sqrtf(4.0f * inv);
        if (1.0f - w > 1e-6f) {
            act1 = true;
            const float sp = sqrtf(mag * inv);
            const float as = sp / fmaxf(sqrtf(mag), 1e-12f);
            q1 = { w, kb1.x*as, kb1.y*as, kb1.z*as };
        }
    }

    // ---- Kogge-Stone inclusive scan of quaternion products (fp32) ----
    Q4 s = qmul(q1, q0);
    #pragma unroll
    for (int d = 1; d < 64; d <<= 1) {
        const Q4 t = shflup_q(s, d);
        if (lane >= d) s = qmul(s, t);
    }
    Q4 ex = shflup_q(s, 1);
    if (lane == 0) ex = {1.f, 0.f, 0.f, 0.f};
    const Q4 Qa = qmul(q0, ex);   // composed rotation up to index i0
    const Q4 Qb = s;              // composed rotation up to index i1

    // ---- last-active-index via ballot + clz ----
    const unsigned long long mask0 = __ballot(act0);   // bit l = act at slot 2l
    const unsigned long long mask1 = __ballot(act1);   // bit l = act at slot 2l+1
    const unsigned long long m0a = mask0 & (~0ull >> (63 - lane));          // bits 0..l (nonempty: bit0 set)
    const unsigned long long m1a = lane ? (mask1 & (~0ull >> (64 - lane))) : 0ull; // bits 0..l-1
    const int j0 = max(2*hbit(m0a), m1a ? 2*hbit(m1a)+1 : -1);
    const unsigned long long m1b = mask1 & (~0ull >> (63 - lane));          // bits 0..l
    const int j1 = max(2*hbit(m0a), m1b ? 2*hbit(m1b)+1 : -1);

    // ---- u_i = R(Q_i) u0 ----
    const F3 uA = qrot(Qa, u0);
    const F3 uB = qrot(Qb, u0);

    // ---- edges at j0/j1: almost always own eA/eB; rare wave-uniform gather ----
    F3 ej0 = eAf, ej1 = eBf;
    if (__any((j0 != i0) || (j1 != i1))) {
        const int s0 = j0 >> 1, s1 = j1 >> 1;
        const F3 a0 = { __shfl(eAf.x, s0, 64), __shfl(eAf.y, s0, 64), __shfl(eAf.z, s0, 64) };
        const F3 b0 = { __shfl(eBf.x, s0, 64), __shfl(eBf.y, s0, 64), __shfl(eBf.z, s0, 64) };
        const F3 a1 = { __shfl(eAf.x, s1, 64), __shfl(eAf.y, s1, 64), __shfl(eAf.z, s1, 64) };
        const F3 b1 = { __shfl(eBf.x, s1, 64), __shfl(eBf.y, s1, 64), __shfl(eBf.z, s1, 64) };
        ej0 = (j0 & 1) ? b0 : a0;
        ej1 = (j1 & 1) ? b1 : a1;
    }

    const F3 vvA = nrmf(crossf(ej0, uA));
    const F3 vvB = nrmf(crossf(ej1, uB));

    // ---- coalesced nontemporal stores: 6 consecutive floats per lane per array ----
    float* bu  = out + (size_t)b * (kNE*3);
    float* bv  = bu  + (size_t)kB * (kNE*3);
    float* kbo = bv  + (size_t)kB * (kNE*3);
    const int o = 6*lane;

    nts2(bu + o    , uA.x, uA.y);
    nts2(bu + o + 2, uA.z, uB.x);
    nts2(bu + o + 4, uB.y, uB.z);

    nts2(bv + o    , vvA.x, vvA.y);
    nts2(bv + o + 2, vvA.z, vvB.x);
    nts2(bv + o + 4, vvB.y, vvB.z);

    nts2(kbo + o    , kb0.x, kb0.y);
    nts2(kbo + o + 2, kb0.z, kb1.x);
    nts2(kbo + o + 4, kb1.y, kb1.z);
}

} // namespace

extern "C" void kernel_launch(void* const* d_in, const int* in_sizes, int n_in,
                              void* d_out, int out_size, void* d_ws, size_t ws_size,
                              hipStream_t stream)
{
    const float* verts = (const float*)d_in[0];
    const float* dinit = (const float*)d_in[1];
    const float* restL = (const float*)d_in[2];
    float* out = (float*)d_out;

    dim3 grid(kB / kRPB);
    dim3 block(64 * kRPB);
    hipLaunchKernelGGL(rod_frames_scan_kernel, grid, block, 0, stream,
                       verts, dinit, restL, out);
}